// Round 1
// baseline (111.928 us; speedup 1.0000x reference)
//
#include <hip/hip_runtime.h>
#include <hip/hip_bf16.h>

#define NB 2048     // batch rows
#define NL 64       // latent dim
#define NN 16       // nuisance dim
#define NROW 80     // NL + NN (z row length)
#define NO 2048     // output dim
#define TPB 256     // threads per block (4 waves)
#define OPT 8       // outputs per thread (2048/256)
#define G 8         // rows per decoder block (grouped by nuisance id)
#define CHUNKS (NB / G)              // 256: worst-case chunks per bucket
#define MBLK (NN * NL * NO / 4 / TPB) // 2048 blocks to build M

typedef unsigned int   u32;
typedef unsigned short u16;

// bf16 (in low/high half of a u32) -> f32
__device__ __forceinline__ float bflo(u32 u) { union { u32 i; float f; } c; c.i = u << 16;          return c.f; }
__device__ __forceinline__ float bfhi(u32 u) { union { u32 i; float f; } c; c.i = u & 0xffff0000u;  return c.f; }
__device__ __forceinline__ u16 f2bf(float f) { __hip_bfloat16 h = __float2bfloat16(f); return *(u16*)&h; }

// ---- Pass 1 (fused): build M = bf16(W+A), bucket rows by argmax id, theta ----
__global__ __launch_bounds__(TPB) void prep(
    const float* __restrict__ W,     // (64, 2048)
    const float* __restrict__ A,     // (16, 64, 2048)
    const float* __restrict__ z,     // (2048, 80)
    const float* __restrict__ pxr,   // (2048,)
    u16* __restrict__ M,             // (16, 64, 2048) bf16
    u32* __restrict__ counts,        // (16,)
    u32* __restrict__ perm,          // (16, 2048) row indices per bucket
    float* __restrict__ out)
{
    const int blk = blockIdx.x;
    const int tid = threadIdx.x;

    if (blk < MBLK) {   // ---- M[id][l][o] = bf16(W[l][o] + A[id][l][o]) ----
        size_t t    = (size_t)blk * TPB + tid;
        size_t base = t * 4;
        float4 w = *(const float4*)(W + (base & (size_t)(NL * NO - 1)));
        float4 a = *(const float4*)(A + base);
        ushort4 m;
        m.x = f2bf(w.x + a.x);
        m.y = f2bf(w.y + a.y);
        m.z = f2bf(w.z + a.z);
        m.w = f2bf(w.w + a.w);
        *(ushort4*)(M + base) = m;
        return;
    }

    if (blk == MBLK) {  // ---- bucket all 2048 rows by nuisance argmax (one block, LDS counts) ----
        __shared__ u32 lc[NN];
        if (tid < NN) lc[tid] = 0;
        __syncthreads();
        #pragma unroll
        for (int k = 0; k < NB / TPB; ++k) {         // 8 rows per thread
            const int b = k * TPB + tid;
            const float* zp = z + (size_t)b * NROW + NL;
            float4 v0 = *(const float4*)(zp);
            float4 v1 = *(const float4*)(zp + 4);
            float4 v2 = *(const float4*)(zp + 8);
            float4 v3 = *(const float4*)(zp + 12);
            float best = v0.x; int bi = 0;           // strict > = first-max tie-break (numpy)
            #define CK(val, idx) if ((val) > best) { best = (val); bi = (idx); }
            CK(v0.y, 1)  CK(v0.z, 2)  CK(v0.w, 3)
            CK(v1.x, 4)  CK(v1.y, 5)  CK(v1.z, 6)  CK(v1.w, 7)
            CK(v2.x, 8)  CK(v2.y, 9)  CK(v2.z, 10) CK(v2.w, 11)
            CK(v3.x, 12) CK(v3.y, 13) CK(v3.z, 14) CK(v3.w, 15)
            #undef CK
            u32 pos = atomicAdd(&lc[bi], 1u);        // order within bucket irrelevant
            perm[(u32)bi * NB + pos] = (u32)b;
        }
        __syncthreads();
        if (tid < NN) counts[tid] = lc[tid];
        return;
    }

    // ---- theta = exp(px_r) ----
    for (int o = tid; o < NO; o += TPB)
        out[(size_t)NB * NO + o] = __expf(pxr[o]);
}

// ---- Pass 2: grouped decoder — G rows of the SAME id per block ----
__global__ __launch_bounds__(TPB) void decoder_g(
    const float* __restrict__ z,     // (2048, 80)
    const float* __restrict__ sf,    // (2048, 1)
    const u16*   __restrict__ M,     // (16, 64, 2048) bf16
    const float* __restrict__ offs,  // (16, 2048)
    const u32*   __restrict__ counts,
    const u32*   __restrict__ perm,
    float* __restrict__ out)
{
    const int bucket = blockIdx.x / CHUNKS;
    const int chunk  = blockIdx.x % CHUNKS;
    const u32 cnt    = counts[bucket];
    if ((u32)(chunk * G) >= cnt) return;             // inactive chunk (block-uniform)
    const int tid = threadIdx.x;

    __shared__ float zt[NL][G];      // z transposed: zt[l][g]
    __shared__ float s_sf[G];
    __shared__ u32   s_rows[G];
    __shared__ float s_red[2][G][4]; // per-wave partial max/sum

    if (tid < G) {
        u32 idx = (u32)(chunk * G + tid);
        u32 clamped = idx < cnt ? idx : (cnt - 1u);  // pad tail with dup row (store guarded)
        u32 r = perm[(size_t)bucket * NB + clamped];
        s_rows[tid] = r;
        s_sf[tid]   = sf[r];
    }
    __syncthreads();
    {   // stage z0 for the 8 rows, transposed for broadcast float4 reads
        const int l = tid & (NL - 1);
        const int g = tid >> 6;                      // 0..3
        u32 r0 = s_rows[g], r1 = s_rows[g + 4];
        zt[l][g]     = z[(size_t)r0 * NROW + l];
        zt[l][g + 4] = z[(size_t)r1 * NROW + l];
    }
    __syncthreads();

    const int o0 = tid * OPT;
    const uint4* mv = (const uint4*)(M + (size_t)bucket * (NL * NO) + o0);

    float acc[G][OPT];
    {
        float4 oa = *(const float4*)(offs + bucket * NO + o0);
        float4 ob = *(const float4*)(offs + bucket * NO + o0 + 4);
        #pragma unroll
        for (int g = 0; g < G; ++g) {
            acc[g][0] = oa.x; acc[g][1] = oa.y; acc[g][2] = oa.z; acc[g][3] = oa.w;
            acc[g][4] = ob.x; acc[g][5] = ob.y; acc[g][6] = ob.z; acc[g][7] = ob.w;
        }
    }

    #pragma unroll 8
    for (int l = 0; l < NL; ++l) {
        const uint4 m = mv[l * (NO / OPT)];
        float v[OPT];                                // unpack ONCE, reuse for 8 rows
        v[0] = bflo(m.x); v[1] = bfhi(m.x);
        v[2] = bflo(m.y); v[3] = bfhi(m.y);
        v[4] = bflo(m.z); v[5] = bfhi(m.z);
        v[6] = bflo(m.w); v[7] = bfhi(m.w);
        const float4 za = *(const float4*)(&zt[l][0]);   // LDS broadcast
        const float4 zb = *(const float4*)(&zt[l][4]);
        const float zg[G] = { za.x, za.y, za.z, za.w, zb.x, zb.y, zb.z, zb.w };
        #pragma unroll
        for (int g = 0; g < G; ++g)
            #pragma unroll
            for (int j = 0; j < OPT; ++j)
                acc[g][j] += zg[g] * v[j];
    }

    // ---- block softmax per row (8 rows) ----
    const int wv = tid >> 6;
    #pragma unroll
    for (int g = 0; g < G; ++g) {
        float m = acc[g][0];
        #pragma unroll
        for (int j = 1; j < OPT; ++j) m = fmaxf(m, acc[g][j]);
        #pragma unroll
        for (int off = 32; off > 0; off >>= 1) m = fmaxf(m, __shfl_down(m, off));
        if ((tid & 63) == 0) s_red[0][g][wv] = m;
    }
    __syncthreads();
    float mx[G];
    #pragma unroll
    for (int g = 0; g < G; ++g)
        mx[g] = fmaxf(fmaxf(s_red[0][g][0], s_red[0][g][1]),
                      fmaxf(s_red[0][g][2], s_red[0][g][3]));

    #pragma unroll
    for (int g = 0; g < G; ++g) {
        float s = 0.f;
        #pragma unroll
        for (int j = 0; j < OPT; ++j) { acc[g][j] = __expf(acc[g][j] - mx[g]); s += acc[g][j]; }
        #pragma unroll
        for (int off = 32; off > 0; off >>= 1) s += __shfl_down(s, off);
        if ((tid & 63) == 0) s_red[1][g][wv] = s;
    }
    __syncthreads();
    #pragma unroll
    for (int g = 0; g < G; ++g) {
        if ((u32)(chunk * G + g) < cnt) {
            const float sm  = (s_red[1][g][0] + s_red[1][g][1]) + (s_red[1][g][2] + s_red[1][g][3]);
            const float scl = s_sf[g] / sm;
            float* op = out + (size_t)s_rows[g] * NO + o0;
            *(float4*)(op)     = make_float4(acc[g][0] * scl, acc[g][1] * scl, acc[g][2] * scl, acc[g][3] * scl);
            *(float4*)(op + 4) = make_float4(acc[g][4] * scl, acc[g][5] * scl, acc[g][6] * scl, acc[g][7] * scl);
        }
    }
}

// ---- Fallback (ws too small): direct fp32 W/A reads, FP32 out ----
__global__ __launch_bounds__(TPB) void decoder_f(
    const float* __restrict__ z, const float* __restrict__ sf,
    const float* __restrict__ W, const float* __restrict__ A,
    const float* __restrict__ offs, const float* __restrict__ pxr,
    float* __restrict__ out)
{
    const int b   = blockIdx.x;
    const int tid = threadIdx.x;
    if (b == NB) {
        for (int o = tid; o < NO; o += TPB)
            out[(size_t)NB * NO + o] = __expf(pxr[o]);
        return;
    }
    __shared__ float z0s[NL];
    __shared__ int   s_id;
    __shared__ float s_red[6];
    if (tid < NL) z0s[tid] = z[b * NROW + tid];
    if (tid == 0) {
        float best = -1e30f; int bi = 0;
        for (int i = 0; i < NN; ++i) {
            float v = z[b * NROW + NL + i];
            if (v > best) { best = v; bi = i; }
        }
        s_id = bi;
    }
    __syncthreads();
    const int id = s_id;
    const int o0 = tid * OPT;
    const float* wp = W + o0;
    const float* ap = A + (size_t)id * NL * NO + o0;
    float acc[OPT];
    {
        float4 oa = *(const float4*)(offs + id * NO + o0);
        float4 ob = *(const float4*)(offs + id * NO + o0 + 4);
        acc[0] = oa.x; acc[1] = oa.y; acc[2] = oa.z; acc[3] = oa.w;
        acc[4] = ob.x; acc[5] = ob.y; acc[6] = ob.z; acc[7] = ob.w;
    }
    #pragma unroll 4
    for (int l = 0; l < NL; ++l) {
        const float zl = z0s[l];
        float4 w0 = *(const float4*)(wp + l * NO);
        float4 w1 = *(const float4*)(wp + l * NO + 4);
        float4 a0 = *(const float4*)(ap + l * NO);
        float4 a1 = *(const float4*)(ap + l * NO + 4);
        acc[0] += zl * (w0.x + a0.x); acc[1] += zl * (w0.y + a0.y);
        acc[2] += zl * (w0.z + a0.z); acc[3] += zl * (w0.w + a0.w);
        acc[4] += zl * (w1.x + a1.x); acc[5] += zl * (w1.y + a1.y);
        acc[6] += zl * (w1.z + a1.z); acc[7] += zl * (w1.w + a1.w);
    }
    float m = acc[0];
    #pragma unroll
    for (int j = 1; j < OPT; ++j) m = fmaxf(m, acc[j]);
    #pragma unroll
    for (int off = 32; off > 0; off >>= 1) m = fmaxf(m, __shfl_down(m, off));
    if ((tid & 63) == 0) s_red[tid >> 6] = m;
    __syncthreads();
    if (tid == 0) s_red[4] = fmaxf(fmaxf(s_red[0], s_red[1]), fmaxf(s_red[2], s_red[3]));
    __syncthreads();
    const float mx = s_red[4];
    float ex[OPT];
    float s = 0.f;
    #pragma unroll
    for (int j = 0; j < OPT; ++j) { ex[j] = __expf(acc[j] - mx); s += ex[j]; }
    #pragma unroll
    for (int off = 32; off > 0; off >>= 1) s += __shfl_down(s, off);
    if ((tid & 63) == 0) s_red[tid >> 6] = s;
    __syncthreads();
    if (tid == 0) s_red[5] = (s_red[0] + s_red[1]) + (s_red[2] + s_red[3]);
    __syncthreads();
    const float scale = sf[b] / s_red[5];
    float* op = out + (size_t)b * NO + o0;
    *(float4*)(op)     = make_float4(ex[0] * scale, ex[1] * scale, ex[2] * scale, ex[3] * scale);
    *(float4*)(op + 4) = make_float4(ex[4] * scale, ex[5] * scale, ex[6] * scale, ex[7] * scale);
}

extern "C" void kernel_launch(void* const* d_in, const int* in_sizes, int n_in,
                              void* d_out, int out_size, void* d_ws, size_t ws_size,
                              hipStream_t stream) {
    const float* z    = (const float*)d_in[0];
    const float* sf   = (const float*)d_in[1];
    const float* W    = (const float*)d_in[2];
    const float* A    = (const float*)d_in[3];
    const float* offs = (const float*)d_in[4];
    const float* pxr  = (const float*)d_in[5];
    float* out = (float*)d_out;

    const size_t m_bytes = (size_t)NN * NL * NO * sizeof(u16);   // 4 MiB
    const size_t need    = m_bytes + 256 + (size_t)NN * NB * sizeof(u32); // + counts/perm
    if (ws_size >= need) {
        u16* M      = (u16*)d_ws;
        u32* counts = (u32*)((char*)d_ws + m_bytes);
        u32* perm   = (u32*)((char*)d_ws + m_bytes + 256);
        hipLaunchKernelGGL(prep, dim3(MBLK + 2), dim3(TPB), 0, stream,
                           W, A, z, pxr, M, counts, perm, out);
        hipLaunchKernelGGL(decoder_g, dim3(NN * CHUNKS), dim3(TPB), 0, stream,
                           z, sf, M, offs, counts, perm, out);
    } else {
        hipLaunchKernelGGL(decoder_f, dim3(NB + 1), dim3(TPB), 0, stream,
                           z, sf, W, A, offs, pxr, out);
    }
}

// Round 2
// 107.627 us; speedup vs baseline: 1.0400x; 1.0400x over previous
//
#include <hip/hip_runtime.h>
#include <hip/hip_bf16.h>

#define NB 2048     // batch rows
#define NL 64       // latent dim
#define NN 16       // nuisance dim
#define NROW 80     // NL + NN (z row length)
#define NO 2048     // output dim
#define TPB 256     // threads per block (4 waves)
#define OPT 8       // outputs per thread (2048/256)
#define G 4         // rows per decoder block (grouped by nuisance id)
#define MAXWL (NB / G + NN)          // 528: max work-list items
#define MBLK (NN * NL * NO / 4 / TPB) // 2048 blocks to build M

typedef unsigned int   u32;
typedef unsigned short u16;

// bf16 (in low/high half of a u32) -> f32
__device__ __forceinline__ float bflo(u32 u) { union { u32 i; float f; } c; c.i = u << 16;          return c.f; }
__device__ __forceinline__ float bfhi(u32 u) { union { u32 i; float f; } c; c.i = u & 0xffff0000u;  return c.f; }
__device__ __forceinline__ u16 f2bf(float f) { __hip_bfloat16 h = __float2bfloat16(f); return *(u16*)&h; }

// ---- Pass 1 (fused): build M = bf16(W+A), bucket rows by argmax id + work list, theta ----
__global__ __launch_bounds__(TPB) void prep(
    const float* __restrict__ W,     // (64, 2048)
    const float* __restrict__ A,     // (16, 64, 2048)
    const float* __restrict__ z,     // (2048, 80)
    const float* __restrict__ pxr,   // (2048,)
    u16* __restrict__ M,             // (16, 64, 2048) bf16
    u32* __restrict__ counts,        // (16,)
    u32* __restrict__ perm,          // (16, 2048) row indices per bucket
    u32* __restrict__ wl,            // (MAXWL,) work items: (bucket<<16)|chunk
    u32* __restrict__ nit,           // (1,) number of work items
    float* __restrict__ out)
{
    const int blk = blockIdx.x;
    const int tid = threadIdx.x;

    if (blk < MBLK) {   // ---- M[id][l][o] = bf16(W[l][o] + A[id][l][o]) ----
        size_t t    = (size_t)blk * TPB + tid;
        size_t base = t * 4;
        float4 w = *(const float4*)(W + (base & (size_t)(NL * NO - 1)));
        float4 a = *(const float4*)(A + base);
        ushort4 m;
        m.x = f2bf(w.x + a.x);
        m.y = f2bf(w.y + a.y);
        m.z = f2bf(w.z + a.z);
        m.w = f2bf(w.w + a.w);
        *(ushort4*)(M + base) = m;
        return;
    }

    if (blk == MBLK) {  // ---- bucket all 2048 rows by nuisance argmax (one block) ----
        __shared__ u32 lc[NN];
        __shared__ u32 choff[NN + 1];
        if (tid < NN) lc[tid] = 0;
        __syncthreads();
        #pragma unroll
        for (int k = 0; k < NB / TPB; ++k) {         // 8 rows per thread
            const int b = k * TPB + tid;
            const float* zp = z + (size_t)b * NROW + NL;
            float4 v0 = *(const float4*)(zp);
            float4 v1 = *(const float4*)(zp + 4);
            float4 v2 = *(const float4*)(zp + 8);
            float4 v3 = *(const float4*)(zp + 12);
            float best = v0.x; int bi = 0;           // strict > = first-max tie-break (numpy)
            #define CK(val, idx) if ((val) > best) { best = (val); bi = (idx); }
            CK(v0.y, 1)  CK(v0.z, 2)  CK(v0.w, 3)
            CK(v1.x, 4)  CK(v1.y, 5)  CK(v1.z, 6)  CK(v1.w, 7)
            CK(v2.x, 8)  CK(v2.y, 9)  CK(v2.z, 10) CK(v2.w, 11)
            CK(v3.x, 12) CK(v3.y, 13) CK(v3.z, 14) CK(v3.w, 15)
            #undef CK
            u32 pos = atomicAdd(&lc[bi], 1u);        // order within bucket irrelevant
            perm[(u32)bi * NB + pos] = (u32)b;
        }
        __syncthreads();
        if (tid == 0) {                              // chunk-offset scan (NN=16, trivial)
            u32 n = 0;
            for (int i = 0; i < NN; ++i) { choff[i] = n; n += (lc[i] + G - 1) / G; }
            choff[NN] = n;
            nit[0] = n;
        }
        __syncthreads();
        if (tid < NN) {
            counts[tid] = lc[tid];
            const u32 nch = (lc[tid] + G - 1) / G;
            const u32 off = choff[tid];
            for (u32 c = 0; c < nch; ++c) wl[off + c] = ((u32)tid << 16) | c;
        }
        return;
    }

    // ---- theta = exp(px_r) ----
    for (int o = tid; o < NO; o += TPB)
        out[(size_t)NB * NO + o] = __expf(pxr[o]);
}

// ---- Pass 2: grouped decoder — G rows of the SAME id per block, compact work list ----
__global__ __launch_bounds__(TPB) void decoder_g(
    const float* __restrict__ z,     // (2048, 80)
    const float* __restrict__ sf,    // (2048, 1)
    const u16*   __restrict__ M,     // (16, 64, 2048) bf16
    const float* __restrict__ offs,  // (16, 2048)
    const u32*   __restrict__ counts,
    const u32*   __restrict__ perm,
    const u32*   __restrict__ wl,
    const u32*   __restrict__ nit,
    float* __restrict__ out)
{
    if (blockIdx.x >= nit[0]) return;                // ≤ NN inactive tail blocks
    const u32 w      = wl[blockIdx.x];
    const int bucket = (int)(w >> 16);
    const int chunk  = (int)(w & 0xffffu);
    const u32 cnt    = counts[bucket];
    const int tid    = threadIdx.x;

    __shared__ float zt[NL][G];      // z transposed: zt[l][g]
    __shared__ float s_sf[G];
    __shared__ u32   s_rows[G];
    __shared__ float s_red[2][G][4]; // per-wave partial max/sum

    if (tid < G) {
        u32 idx = (u32)(chunk * G + tid);
        u32 clamped = idx < cnt ? idx : (cnt - 1u);  // pad tail with dup row (store guarded)
        u32 r = perm[(size_t)bucket * NB + clamped];
        s_rows[tid] = r;
        s_sf[tid]   = sf[r];
    }
    __syncthreads();
    {   // stage z0 for the G rows, transposed for broadcast float4 reads (256 = NL*G threads)
        const int l = tid & (NL - 1);
        const int g = tid >> 6;                      // 0..3
        zt[l][g] = z[(size_t)s_rows[g] * NROW + l];
    }
    __syncthreads();

    const int o0 = tid * OPT;
    const uint4* mv = (const uint4*)(M + (size_t)bucket * (NL * NO) + o0);

    float acc[G][OPT];
    {
        float4 oa = *(const float4*)(offs + bucket * NO + o0);
        float4 ob = *(const float4*)(offs + bucket * NO + o0 + 4);
        #pragma unroll
        for (int g = 0; g < G; ++g) {
            acc[g][0] = oa.x; acc[g][1] = oa.y; acc[g][2] = oa.z; acc[g][3] = oa.w;
            acc[g][4] = ob.x; acc[g][5] = ob.y; acc[g][6] = ob.z; acc[g][7] = ob.w;
        }
    }

    #pragma unroll 8
    for (int l = 0; l < NL; ++l) {
        const uint4 m = mv[l * (NO / OPT)];
        float v[OPT];                                // unpack ONCE, reuse for G rows
        v[0] = bflo(m.x); v[1] = bfhi(m.x);
        v[2] = bflo(m.y); v[3] = bfhi(m.y);
        v[4] = bflo(m.z); v[5] = bfhi(m.z);
        v[6] = bflo(m.w); v[7] = bfhi(m.w);
        const float4 za = *(const float4*)(&zt[l][0]);   // LDS broadcast
        const float zg[G] = { za.x, za.y, za.z, za.w };
        #pragma unroll
        for (int g = 0; g < G; ++g)
            #pragma unroll
            for (int j = 0; j < OPT; ++j)
                acc[g][j] += zg[g] * v[j];
    }

    // ---- block softmax per row (G rows) ----
    const int wv = tid >> 6;
    #pragma unroll
    for (int g = 0; g < G; ++g) {
        float m = acc[g][0];
        #pragma unroll
        for (int j = 1; j < OPT; ++j) m = fmaxf(m, acc[g][j]);
        #pragma unroll
        for (int off = 32; off > 0; off >>= 1) m = fmaxf(m, __shfl_down(m, off));
        if ((tid & 63) == 0) s_red[0][g][wv] = m;
    }
    __syncthreads();
    float mx[G];
    #pragma unroll
    for (int g = 0; g < G; ++g)
        mx[g] = fmaxf(fmaxf(s_red[0][g][0], s_red[0][g][1]),
                      fmaxf(s_red[0][g][2], s_red[0][g][3]));

    #pragma unroll
    for (int g = 0; g < G; ++g) {
        float s = 0.f;
        #pragma unroll
        for (int j = 0; j < OPT; ++j) { acc[g][j] = __expf(acc[g][j] - mx[g]); s += acc[g][j]; }
        #pragma unroll
        for (int off = 32; off > 0; off >>= 1) s += __shfl_down(s, off);
        if ((tid & 63) == 0) s_red[1][g][wv] = s;
    }
    __syncthreads();
    #pragma unroll
    for (int g = 0; g < G; ++g) {
        if ((u32)(chunk * G + g) < cnt) {
            const float sm  = (s_red[1][g][0] + s_red[1][g][1]) + (s_red[1][g][2] + s_red[1][g][3]);
            const float scl = s_sf[g] / sm;
            float* op = out + (size_t)s_rows[g] * NO + o0;
            *(float4*)(op)     = make_float4(acc[g][0] * scl, acc[g][1] * scl, acc[g][2] * scl, acc[g][3] * scl);
            *(float4*)(op + 4) = make_float4(acc[g][4] * scl, acc[g][5] * scl, acc[g][6] * scl, acc[g][7] * scl);
        }
    }
}

// ---- Fallback (ws too small): direct fp32 W/A reads, FP32 out ----
__global__ __launch_bounds__(TPB) void decoder_f(
    const float* __restrict__ z, const float* __restrict__ sf,
    const float* __restrict__ W, const float* __restrict__ A,
    const float* __restrict__ offs, const float* __restrict__ pxr,
    float* __restrict__ out)
{
    const int b   = blockIdx.x;
    const int tid = threadIdx.x;
    if (b == NB) {
        for (int o = tid; o < NO; o += TPB)
            out[(size_t)NB * NO + o] = __expf(pxr[o]);
        return;
    }
    __shared__ float z0s[NL];
    __shared__ int   s_id;
    __shared__ float s_red[6];
    if (tid < NL) z0s[tid] = z[b * NROW + tid];
    if (tid == 0) {
        float best = -1e30f; int bi = 0;
        for (int i = 0; i < NN; ++i) {
            float v = z[b * NROW + NL + i];
            if (v > best) { best = v; bi = i; }
        }
        s_id = bi;
    }
    __syncthreads();
    const int id = s_id;
    const int o0 = tid * OPT;
    const float* wp = W + o0;
    const float* ap = A + (size_t)id * NL * NO + o0;
    float acc[OPT];
    {
        float4 oa = *(const float4*)(offs + id * NO + o0);
        float4 ob = *(const float4*)(offs + id * NO + o0 + 4);
        acc[0] = oa.x; acc[1] = oa.y; acc[2] = oa.z; acc[3] = oa.w;
        acc[4] = ob.x; acc[5] = ob.y; acc[6] = ob.z; acc[7] = ob.w;
    }
    #pragma unroll 4
    for (int l = 0; l < NL; ++l) {
        const float zl = z0s[l];
        float4 w0 = *(const float4*)(wp + l * NO);
        float4 w1 = *(const float4*)(wp + l * NO + 4);
        float4 a0 = *(const float4*)(ap + l * NO);
        float4 a1 = *(const float4*)(ap + l * NO + 4);
        acc[0] += zl * (w0.x + a0.x); acc[1] += zl * (w0.y + a0.y);
        acc[2] += zl * (w0.z + a0.z); acc[3] += zl * (w0.w + a0.w);
        acc[4] += zl * (w1.x + a1.x); acc[5] += zl * (w1.y + a1.y);
        acc[6] += zl * (w1.z + a1.z); acc[7] += zl * (w1.w + a1.w);
    }
    float m = acc[0];
    #pragma unroll
    for (int j = 1; j < OPT; ++j) m = fmaxf(m, acc[j]);
    #pragma unroll
    for (int off = 32; off > 0; off >>= 1) m = fmaxf(m, __shfl_down(m, off));
    if ((tid & 63) == 0) s_red[tid >> 6] = m;
    __syncthreads();
    if (tid == 0) s_red[4] = fmaxf(fmaxf(s_red[0], s_red[1]), fmaxf(s_red[2], s_red[3]));
    __syncthreads();
    const float mx = s_red[4];
    float ex[OPT];
    float s = 0.f;
    #pragma unroll
    for (int j = 0; j < OPT; ++j) { ex[j] = __expf(acc[j] - mx); s += ex[j]; }
    #pragma unroll
    for (int off = 32; off > 0; off >>= 1) s += __shfl_down(s, off);
    if ((tid & 63) == 0) s_red[tid >> 6] = s;
    __syncthreads();
    if (tid == 0) s_red[5] = (s_red[0] + s_red[1]) + (s_red[2] + s_red[3]);
    __syncthreads();
    const float scale = sf[b] / s_red[5];
    float* op = out + (size_t)b * NO + o0;
    *(float4*)(op)     = make_float4(ex[0] * scale, ex[1] * scale, ex[2] * scale, ex[3] * scale);
    *(float4*)(op + 4) = make_float4(ex[4] * scale, ex[5] * scale, ex[6] * scale, ex[7] * scale);
}

extern "C" void kernel_launch(void* const* d_in, const int* in_sizes, int n_in,
                              void* d_out, int out_size, void* d_ws, size_t ws_size,
                              hipStream_t stream) {
    const float* z    = (const float*)d_in[0];
    const float* sf   = (const float*)d_in[1];
    const float* W    = (const float*)d_in[2];
    const float* A    = (const float*)d_in[3];
    const float* offs = (const float*)d_in[4];
    const float* pxr  = (const float*)d_in[5];
    float* out = (float*)d_out;

    const size_t m_bytes = (size_t)NN * NL * NO * sizeof(u16);   // 4 MiB
    const size_t p_bytes = (size_t)NN * NB * sizeof(u32);        // 128 KiB perm
    const size_t need    = m_bytes + 256 + p_bytes + (MAXWL + 64) * sizeof(u32);
    if (ws_size >= need) {
        u16* M      = (u16*)d_ws;
        u32* counts = (u32*)((char*)d_ws + m_bytes);
        u32* perm   = (u32*)((char*)d_ws + m_bytes + 256);
        u32* wl     = (u32*)((char*)d_ws + m_bytes + 256 + p_bytes);
        u32* nit    = wl + MAXWL;
        hipLaunchKernelGGL(prep, dim3(MBLK + 2), dim3(TPB), 0, stream,
                           W, A, z, pxr, M, counts, perm, wl, nit, out);
        hipLaunchKernelGGL(decoder_g, dim3(MAXWL), dim3(TPB), 0, stream,
                           z, sf, M, offs, counts, perm, wl, nit, out);
    } else {
        hipLaunchKernelGGL(decoder_f, dim3(NB + 1), dim3(TPB), 0, stream,
                           z, sf, W, A, offs, pxr, out);
    }
}

// Round 3
// 100.429 us; speedup vs baseline: 1.1145x; 1.0717x over previous
//
#include <hip/hip_runtime.h>
#include <hip/hip_bf16.h>

#define NB 2048     // batch rows
#define NL 64       // latent dim
#define NN 16       // nuisance dim
#define NROW 80     // NL + NN (z row length)
#define NO 2048     // output dim
#define TPB 256     // threads per block (prep / fallback)
#define TPB_D 512   // decoder threads (8 waves)
#define G 16        // rows per decoder block (one 16-row MFMA tile)
#define MAXWL (NB / G + NN)   // 144 work items max
#define PBLK 256    // Mt build blocks: 16 buckets x 8 o-chunks x 2 k-halves
#define OPT 8       // fallback outputs/thread

typedef unsigned int   u32;
typedef unsigned short u16;
typedef __attribute__((ext_vector_type(8))) short short8;  // bf16x8 MFMA operand
typedef __attribute__((ext_vector_type(4))) float f32x4;   // MFMA accumulator

__device__ __forceinline__ float bflo(u32 u) { union { u32 i; float f; } c; c.i = u << 16;          return c.f; }
__device__ __forceinline__ u16 f2bf(float f) { __hip_bfloat16 h = __float2bfloat16(f); return *(u16*)&h; }

__device__ __forceinline__ f32x4 mfma16(short8 a, short8 b, f32x4 c) {
    return __builtin_amdgcn_mfma_f32_16x16x32_bf16(a, b, c, 0, 0, 0);
}

// ---- Pass 1 (fused): build Mt[bucket][o][k] = bf16(W[k][o]+A[bucket][k][o]),
// ----                 bucket rows by argmax id + work list, theta ----
__global__ __launch_bounds__(TPB) void prep(
    const float* __restrict__ W,     // (64, 2048)
    const float* __restrict__ A,     // (16, 64, 2048)
    const float* __restrict__ z,     // (2048, 80)
    const float* __restrict__ pxr,   // (2048,)
    u16* __restrict__ Mt,            // (16, 2048, 64) bf16, k-major rows
    u32* __restrict__ counts,        // (16,)
    u32* __restrict__ perm,          // (16, 2048)
    u32* __restrict__ wl,            // (MAXWL,) items: (bucket<<16)|chunk
    u32* __restrict__ nit,           // (1,)
    float* __restrict__ out)
{
    const int blk = blockIdx.x;
    const int tid = threadIdx.x;

    if (blk < PBLK) {   // ---- transposed M build ----
        const int bucket = blk >> 4;
        const int rem    = blk & 15;
        const int och    = rem >> 1;        // 0..7 (256-output chunk)
        const int k0     = (rem & 1) * 32;  // k-half
        const int o      = (och << 8) | tid;
        const float* wp = W + (size_t)k0 * NO + o;
        const float* ap = A + (size_t)bucket * NL * NO + (size_t)k0 * NO + o;
        u32 pk[16];
        #pragma unroll
        for (int j = 0; j < 16; ++j) {      // 32 k-rows, coalesced 1KB/instr
            float v0 = wp[(2 * j) * NO]     + ap[(2 * j) * NO];
            float v1 = wp[(2 * j + 1) * NO] + ap[(2 * j + 1) * NO];
            pk[j] = (u32)f2bf(v0) | ((u32)f2bf(v1) << 16);
        }
        u16* row = Mt + ((size_t)bucket * NO + o) * NL + k0;
        #pragma unroll
        for (int i = 0; i < 4; ++i)
            *(uint4*)(row + i * 8) = make_uint4(pk[4 * i], pk[4 * i + 1], pk[4 * i + 2], pk[4 * i + 3]);
        return;
    }

    if (blk == PBLK) {  // ---- bucket all rows by nuisance argmax (one block) ----
        __shared__ u32 lc[NN];
        __shared__ u32 choff[NN + 1];
        if (tid < NN) lc[tid] = 0;
        __syncthreads();
        #pragma unroll
        for (int k = 0; k < NB / TPB; ++k) {
            const int b = k * TPB + tid;
            const float* zp = z + (size_t)b * NROW + NL;
            float4 v0 = *(const float4*)(zp);
            float4 v1 = *(const float4*)(zp + 4);
            float4 v2 = *(const float4*)(zp + 8);
            float4 v3 = *(const float4*)(zp + 12);
            float best = v0.x; int bi = 0;   // strict > = first-max tie-break
            #define CK(val, idx) if ((val) > best) { best = (val); bi = (idx); }
            CK(v0.y, 1)  CK(v0.z, 2)  CK(v0.w, 3)
            CK(v1.x, 4)  CK(v1.y, 5)  CK(v1.z, 6)  CK(v1.w, 7)
            CK(v2.x, 8)  CK(v2.y, 9)  CK(v2.z, 10) CK(v2.w, 11)
            CK(v3.x, 12) CK(v3.y, 13) CK(v3.z, 14) CK(v3.w, 15)
            #undef CK
            u32 pos = atomicAdd(&lc[bi], 1u);
            perm[(u32)bi * NB + pos] = (u32)b;
        }
        __syncthreads();
        if (tid == 0) {
            u32 n = 0;
            for (int i = 0; i < NN; ++i) { choff[i] = n; n += (lc[i] + G - 1) / G; }
            nit[0] = n;
        }
        __syncthreads();
        if (tid < NN) {
            counts[tid] = lc[tid];
            const u32 nch = (lc[tid] + G - 1) / G;
            const u32 off = choff[tid];
            for (u32 c = 0; c < nch; ++c) wl[off + c] = ((u32)tid << 16) | c;
        }
        return;
    }

    // ---- theta = exp(px_r) ----
    for (int o = tid; o < NO; o += TPB)
        out[(size_t)NB * NO + o] = __expf(pxr[o]);
}

// ---- Pass 2: MFMA decoder — 16 rows of one bucket per block, 8 waves x 256 cols ----
__global__ __launch_bounds__(TPB_D) void decoder_t(
    const float* __restrict__ z,
    const float* __restrict__ sf,
    const u16*   __restrict__ Mt,    // (16, 2048, 64) bf16
    const float* __restrict__ offs,  // (16, 2048)
    const u32*   __restrict__ counts,
    const u32*   __restrict__ perm,
    const u32*   __restrict__ wl,
    const u32*   __restrict__ nit,
    float* __restrict__ out)
{
    if (blockIdx.x >= nit[0]) return;
    const u32 w      = wl[blockIdx.x];
    const int bucket = (int)(w >> 16);
    const int chunk  = (int)(w & 0xffffu);
    const u32 cnt    = counts[bucket];
    const int tid  = threadIdx.x;
    const int lane = tid & 63;
    const int wv   = tid >> 6;       // 0..7
    const int r    = lane & 15;      // batch-row slot (B col / D col)
    const int q    = lane >> 4;      // 0..3 quad (k-group / D row-quad)

    __shared__ u32   s_rows[G];
    __shared__ float s_sf[G];
    __shared__ float red[2][G][8];

    if (tid < G) {
        u32 idx = (u32)(chunk * G + tid);
        u32 cl  = idx < cnt ? idx : cnt - 1u;   // pad tail with dup row; stores guarded
        u32 rr  = perm[(size_t)bucket * NB + cl];
        s_rows[tid] = rr;
        s_sf[tid]   = sf[rr];
    }
    __syncthreads();

    // B fragments: z row split hi/lo bf16 (z = zhi + zlo keeps z at ~fp32 precision)
    union BF { short8 s; u32 u[4]; };
    BF bh[2], bl[2];
    {
        const float* zp = z + (size_t)s_rows[r] * NROW + (q << 3);
        #pragma unroll
        for (int kk = 0; kk < 2; ++kk) {
            float4 za = *(const float4*)(zp + kk * 32);
            float4 zb = *(const float4*)(zp + kk * 32 + 4);
            float e[8] = { za.x, za.y, za.z, za.w, zb.x, zb.y, zb.z, zb.w };
            #pragma unroll
            for (int j = 0; j < 4; ++j) {
                u16 h0 = f2bf(e[2 * j]);
                u16 h1 = f2bf(e[2 * j + 1]);
                float l0 = e[2 * j]     - bflo(h0);
                float l1 = e[2 * j + 1] - bflo(h1);
                bh[kk].u[j] = (u32)h0 | ((u32)h1 << 16);
                bl[kk].u[j] = (u32)f2bf(l0) | ((u32)f2bf(l1) << 16);
            }
        }
    }

    // 16 output tiles per wave: D^T[o][r] = Mt[o][k] * z[r][k], C init = offsets
    f32x4 acc[16];
    const u16*   mtb = Mt   + (size_t)bucket * NO * NL;
    const float* ofb = offs + (size_t)bucket * NO;
    #pragma unroll
    for (int t = 0; t < 16; ++t) {
        const int tg = (wv << 4) + t;                        // global 16-col tile
        const u16* ar = mtb + ((size_t)((tg << 4) + r)) * NL + (q << 3);
        uint4 a0r = *(const uint4*)(ar);                     // k = q*8..q*8+7
        uint4 a1r = *(const uint4*)(ar + 32);                // k = 32+q*8..
        short8 a0, a1;
        __builtin_memcpy(&a0, &a0r, 16);
        __builtin_memcpy(&a1, &a1r, 16);
        float4 of = *(const float4*)(ofb + (tg << 4) + (q << 2));
        f32x4 c = { of.x, of.y, of.z, of.w };
        c = mfma16(a0, bh[0].s, c);
        c = mfma16(a1, bh[1].s, c);
        c = mfma16(a0, bl[0].s, c);
        c = mfma16(a1, bl[1].s, c);
        acc[t] = c;
    }

    // ---- softmax: each lane holds 64 outputs of batch row r ----
    float mx = acc[0][0];
    #pragma unroll
    for (int t = 0; t < 16; ++t)
        #pragma unroll
        for (int j = 0; j < 4; ++j) mx = fmaxf(mx, acc[t][j]);
    mx = fmaxf(mx, __shfl_xor(mx, 16));
    mx = fmaxf(mx, __shfl_xor(mx, 32));
    if (lane < G) red[0][lane][wv] = mx;
    __syncthreads();
    float m = red[0][r][0];
    #pragma unroll
    for (int i = 1; i < 8; ++i) m = fmaxf(m, red[0][r][i]);

    float s = 0.f;
    #pragma unroll
    for (int t = 0; t < 16; ++t)
        #pragma unroll
        for (int j = 0; j < 4; ++j) {
            float e = __expf(acc[t][j] - m);
            acc[t][j] = e;
            s += e;
        }
    s += __shfl_xor(s, 16);
    s += __shfl_xor(s, 32);
    if (lane < G) red[1][lane][wv] = s;
    __syncthreads();
    float tot = red[1][r][0];
    #pragma unroll
    for (int i = 1; i < 8; ++i) tot += red[1][r][i];

    if ((u32)(chunk * G + r) < cnt) {
        const float scl = s_sf[r] / tot;
        float* ob = out + (size_t)s_rows[r] * NO;
        #pragma unroll
        for (int t = 0; t < 16; ++t) {
            const int tg = (wv << 4) + t;
            *(float4*)(ob + (tg << 4) + (q << 2)) =
                make_float4(acc[t][0] * scl, acc[t][1] * scl, acc[t][2] * scl, acc[t][3] * scl);
        }
    }
}

// ---- Fallback (ws too small): direct fp32 W/A reads, FP32 out ----
__global__ __launch_bounds__(TPB) void decoder_f(
    const float* __restrict__ z, const float* __restrict__ sf,
    const float* __restrict__ W, const float* __restrict__ A,
    const float* __restrict__ offs, const float* __restrict__ pxr,
    float* __restrict__ out)
{
    const int b   = blockIdx.x;
    const int tid = threadIdx.x;
    if (b == NB) {
        for (int o = tid; o < NO; o += TPB)
            out[(size_t)NB * NO + o] = __expf(pxr[o]);
        return;
    }
    __shared__ float z0s[NL];
    __shared__ int   s_id;
    __shared__ float s_red[6];
    if (tid < NL) z0s[tid] = z[b * NROW + tid];
    if (tid == 0) {
        float best = -1e30f; int bi = 0;
        for (int i = 0; i < NN; ++i) {
            float v = z[b * NROW + NL + i];
            if (v > best) { best = v; bi = i; }
        }
        s_id = bi;
    }
    __syncthreads();
    const int id = s_id;
    const int o0 = tid * OPT;
    const float* wp = W + o0;
    const float* ap = A + (size_t)id * NL * NO + o0;
    float acc[OPT];
    {
        float4 oa = *(const float4*)(offs + id * NO + o0);
        float4 ob = *(const float4*)(offs + id * NO + o0 + 4);
        acc[0] = oa.x; acc[1] = oa.y; acc[2] = oa.z; acc[3] = oa.w;
        acc[4] = ob.x; acc[5] = ob.y; acc[6] = ob.z; acc[7] = ob.w;
    }
    #pragma unroll 4
    for (int l = 0; l < NL; ++l) {
        const float zl = z0s[l];
        float4 w0 = *(const float4*)(wp + l * NO);
        float4 w1 = *(const float4*)(wp + l * NO + 4);
        float4 a0 = *(const float4*)(ap + l * NO);
        float4 a1 = *(const float4*)(ap + l * NO + 4);
        acc[0] += zl * (w0.x + a0.x); acc[1] += zl * (w0.y + a0.y);
        acc[2] += zl * (w0.z + a0.z); acc[3] += zl * (w0.w + a0.w);
        acc[4] += zl * (w1.x + a1.x); acc[5] += zl * (w1.y + a1.y);
        acc[6] += zl * (w1.z + a1.z); acc[7] += zl * (w1.w + a1.w);
    }
    float m = acc[0];
    #pragma unroll
    for (int j = 1; j < OPT; ++j) m = fmaxf(m, acc[j]);
    #pragma unroll
    for (int off = 32; off > 0; off >>= 1) m = fmaxf(m, __shfl_down(m, off));
    if ((tid & 63) == 0) s_red[tid >> 6] = m;
    __syncthreads();
    if (tid == 0) s_red[4] = fmaxf(fmaxf(s_red[0], s_red[1]), fmaxf(s_red[2], s_red[3]));
    __syncthreads();
    const float mx = s_red[4];
    float ex[OPT];
    float s = 0.f;
    #pragma unroll
    for (int j = 0; j < OPT; ++j) { ex[j] = __expf(acc[j] - mx); s += ex[j]; }
    #pragma unroll
    for (int off = 32; off > 0; off >>= 1) s += __shfl_down(s, off);
    if ((tid & 63) == 0) s_red[tid >> 6] = s;
    __syncthreads();
    if (tid == 0) s_red[5] = (s_red[0] + s_red[1]) + (s_red[2] + s_red[3]);
    __syncthreads();
    const float scale = sf[b] / s_red[5];
    float* op = out + (size_t)b * NO + o0;
    *(float4*)(op)     = make_float4(ex[0] * scale, ex[1] * scale, ex[2] * scale, ex[3] * scale);
    *(float4*)(op + 4) = make_float4(ex[4] * scale, ex[5] * scale, ex[6] * scale, ex[7] * scale);
}

extern "C" void kernel_launch(void* const* d_in, const int* in_sizes, int n_in,
                              void* d_out, int out_size, void* d_ws, size_t ws_size,
                              hipStream_t stream) {
    const float* z    = (const float*)d_in[0];
    const float* sf   = (const float*)d_in[1];
    const float* W    = (const float*)d_in[2];
    const float* A    = (const float*)d_in[3];
    const float* offs = (const float*)d_in[4];
    const float* pxr  = (const float*)d_in[5];
    float* out = (float*)d_out;

    const size_t m_bytes = (size_t)NN * NL * NO * sizeof(u16);   // 4 MiB Mt
    const size_t p_bytes = (size_t)NN * NB * sizeof(u32);        // 128 KiB perm
    const size_t need    = m_bytes + 256 + p_bytes + (MAXWL + 64) * sizeof(u32);
    if (ws_size >= need) {
        u16* Mt     = (u16*)d_ws;
        u32* counts = (u32*)((char*)d_ws + m_bytes);
        u32* perm   = (u32*)((char*)d_ws + m_bytes + 256);
        u32* wl     = (u32*)((char*)d_ws + m_bytes + 256 + p_bytes);
        u32* nit    = wl + MAXWL;
        hipLaunchKernelGGL(prep, dim3(PBLK + 2), dim3(TPB), 0, stream,
                           W, A, z, pxr, Mt, counts, perm, wl, nit, out);
        hipLaunchKernelGGL(decoder_t, dim3(MAXWL), dim3(TPB_D), 0, stream,
                           z, sf, Mt, offs, counts, perm, wl, nit, out);
    } else {
        hipLaunchKernelGGL(decoder_f, dim3(NB + 1), dim3(TPB), 0, stream,
                           z, sf, W, A, offs, pxr, out);
    }
}